// Round 12
// baseline (365.134 us; speedup 1.0000x reference)
//
#include <hip/hip_runtime.h>
#include <hip/hip_bf16.h>

// Problem constants: B=32768, D=768, C=200.
#define NROWS 32768
#define DIMS  768
#define NC    200
#define CPAD  256
#define KSTEP 32
#define NSTEP (DIMS / KSTEP)   // 24
#define ROWSB 64               // M-tile rows per block

typedef __attribute__((ext_vector_type(8))) short short8;   // 8 bf16
typedef __attribute__((ext_vector_type(4))) float f32x4;

__device__ __forceinline__ unsigned pk_bf16(float lo, float hi) {
  union { __hip_bfloat162 h; unsigned u; } c;
  c.h = __float22bfloat162_rn(make_float2(lo, hi));
  return c.u;
}

// Kernel 1 (round-6 verbatim): L2-normalize centers -> bf16, K-blocked:
// (c,d) -> cnb2[(d>>5)*CPAD*KSTEP + c*KSTEP + (d&31)]; rows >= NC zero. Zeroes out.
__global__ __launch_bounds__(256) void prep_centers_k(const float* __restrict__ centers,
                                                      short* __restrict__ cnb2,
                                                      float* __restrict__ out) {
  const int c = blockIdx.x;
  const int tid = threadIdx.x;
  if (c == 0 && tid == 0) out[0] = 0.f;
  if (c >= NC) {
    for (int d = tid; d < DIMS; d += 256)
      cnb2[(d >> 5) * (CPAD * KSTEP) + c * KSTEP + (d & 31)] = 0;
    return;
  }
  float ssq = 0.f;
  for (int d = tid; d < DIMS; d += 256) {
    float v = centers[c * DIMS + d];
    ssq += v * v;
  }
#pragma unroll
  for (int off = 32; off > 0; off >>= 1) ssq += __shfl_down(ssq, off);
  __shared__ float red[4];
  const int wid = tid >> 6, lane = tid & 63;
  if (lane == 0) red[wid] = ssq;
  __syncthreads();
  const float tot = red[0] + red[1] + red[2] + red[3];
  const float inv = 1.f / fmaxf(sqrtf(tot), 1e-8f);
  for (int d = tid; d < DIMS; d += 256) {
    const float v = centers[c * DIMS + d] * inv;
    union { __hip_bfloat16 h; short s; } cv;
    cv.h = __float2bfloat16(v);
    cnb2[(d >> 5) * (CPAD * KSTEP) + c * KSTEP + (d & 31)] = cv.s;
  }
}

// Kernel 2: ROUND-6 BEST (38.0 us) — dbuf LDS GEMM, unchanged.
__global__ __launch_bounds__(256) void cos_loss_k(
    const float* __restrict__ feats,
    const short* __restrict__ cnb2,
    const int* __restrict__ labels,
    const int* __restrict__ labelled,
    float* __restrict__ out) {
  const int tid = threadIdx.x;
  const int w = tid >> 6;
  const int lane = tid & 63;
  const int m = lane & 15;
  const int kg = lane >> 4;
  const int swzf = (m >> 1) & 3;
  const int rowBase = blockIdx.x * ROWSB;

  __shared__ short As[2][ROWSB][32];
  __shared__ short Bs[2][CPAD][32];
  __shared__ float invs[ROWSB];
  __shared__ int   labLds[ROWSB];
  __shared__ int   lblLds[ROWSB];
  __shared__ float l1part[4][ROWSB];
  __shared__ float alpart[4][ROWSB];

  if (tid < ROWSB) {
    labLds[tid] = labels[rowBase + tid];
    lblLds[tid] = labelled[rowBase + tid];
  }

  const int arow = tid >> 2;
  const int akg  = tid & 3;
  const int aswz = (arow >> 1) & 3;
  const float* asrc = feats + (size_t)(rowBase + arow) * DIMS + akg * 8;
  const int bcol = tid;
  const int bswz = (bcol >> 1) & 3;
  const short* bsrc = cnb2 + bcol * KSTEP;

  f32x4 acc[4][4];
#pragma unroll
  for (int mi = 0; mi < 4; ++mi)
#pragma unroll
    for (int ni = 0; ni < 4; ++ni) acc[mi][ni] = (f32x4){0.f, 0.f, 0.f, 0.f};

  float ssq = 0.f;

  {
    const float4 va = *(const float4*)(asrc);
    const float4 vb = *(const float4*)(asrc + 4);
    ssq += va.x*va.x + va.y*va.y + va.z*va.z + va.w*va.w;
    ssq += vb.x*vb.x + vb.y*vb.y + vb.z*vb.z + vb.w*vb.w;
    union { short8 s; unsigned u[4]; } p;
    p.u[0] = pk_bf16(va.x, va.y); p.u[1] = pk_bf16(va.z, va.w);
    p.u[2] = pk_bf16(vb.x, vb.y); p.u[3] = pk_bf16(vb.z, vb.w);
    *(short8*)(&As[0][arow][(akg ^ aswz) * 8]) = p.s;
    const short8 b0 = *(const short8*)(bsrc + 0);
    const short8 b1 = *(const short8*)(bsrc + 8);
    const short8 b2 = *(const short8*)(bsrc + 16);
    const short8 b3 = *(const short8*)(bsrc + 24);
    *(short8*)(&Bs[0][bcol][(0 ^ bswz) * 8]) = b0;
    *(short8*)(&Bs[0][bcol][(1 ^ bswz) * 8]) = b1;
    *(short8*)(&Bs[0][bcol][(2 ^ bswz) * 8]) = b2;
    *(short8*)(&Bs[0][bcol][(3 ^ bswz) * 8]) = b3;
  }
  __syncthreads();

#pragma unroll 2
  for (int ks = 0; ks < NSTEP; ++ks) {
    const int cur = ks & 1, nxt = cur ^ 1;
    float4 va, vb;
    short8 b0, b1, b2, b3;
    if (ks < NSTEP - 1) {
      const float* ap = asrc + (ks + 1) * KSTEP;
      va = *(const float4*)(ap);
      vb = *(const float4*)(ap + 4);
      const short* bp = bsrc + (size_t)(ks + 1) * (CPAD * KSTEP);
      b0 = *(const short8*)(bp + 0);
      b1 = *(const short8*)(bp + 8);
      b2 = *(const short8*)(bp + 16);
      b3 = *(const short8*)(bp + 24);
    }
    {
      short8 af[4], bf[4];
#pragma unroll
      for (int mi = 0; mi < 4; ++mi)
        af[mi] = *(const short8*)(&As[cur][mi * 16 + m][(kg ^ swzf) * 8]);
#pragma unroll
      for (int ni = 0; ni < 4; ++ni)
        bf[ni] = *(const short8*)(&Bs[cur][w * 64 + ni * 16 + m][(kg ^ swzf) * 8]);
#pragma unroll
      for (int mi = 0; mi < 4; ++mi)
#pragma unroll
        for (int ni = 0; ni < 4; ++ni)
          acc[mi][ni] = __builtin_amdgcn_mfma_f32_16x16x32_bf16(af[mi], bf[ni], acc[mi][ni], 0, 0, 0);
    }
    if (ks < NSTEP - 1) {
      ssq += va.x*va.x + va.y*va.y + va.z*va.z + va.w*va.w;
      ssq += vb.x*vb.x + vb.y*vb.y + vb.z*vb.z + vb.w*vb.w;
      union { short8 s; unsigned u[4]; } p;
      p.u[0] = pk_bf16(va.x, va.y); p.u[1] = pk_bf16(va.z, va.w);
      p.u[2] = pk_bf16(vb.x, vb.y); p.u[3] = pk_bf16(vb.z, vb.w);
      *(short8*)(&As[nxt][arow][(akg ^ aswz) * 8]) = p.s;
      *(short8*)(&Bs[nxt][bcol][(0 ^ bswz) * 8]) = b0;
      *(short8*)(&Bs[nxt][bcol][(1 ^ bswz) * 8]) = b1;
      *(short8*)(&Bs[nxt][bcol][(2 ^ bswz) * 8]) = b2;
      *(short8*)(&Bs[nxt][bcol][(3 ^ bswz) * 8]) = b3;
    }
    __syncthreads();
  }

  ssq += __shfl_xor(ssq, 1);
  ssq += __shfl_xor(ssq, 2);
  if ((tid & 3) == 0) invs[arow] = 1.f / fmaxf(sqrtf(ssq), 1e-8f);
  __syncthreads();

#pragma unroll
  for (int mi = 0; mi < 4; ++mi) {
    float l1r[4] = {0.f, 0.f, 0.f, 0.f};
    float alr[4] = {0.f, 0.f, 0.f, 0.f};
    float iv[4];
    int labr[4];
#pragma unroll
    for (int r = 0; r < 4; ++r) {
      const int row = mi * 16 + kg * 4 + r;
      iv[r] = invs[row];
      labr[r] = labLds[row];
    }
#pragma unroll
    for (int ni = 0; ni < 4; ++ni) {
      const int col = w * 64 + ni * 16 + m;
#pragma unroll
      for (int r = 0; r < 4; ++r) {
        const float a = fabsf(acc[mi][ni][r] * iv[r]);
        l1r[r] += a;
        if (col == labr[r]) alr[r] += a;
      }
    }
#pragma unroll
    for (int r = 0; r < 4; ++r) {
#pragma unroll
      for (int off = 1; off < 16; off <<= 1) {
        l1r[r] += __shfl_xor(l1r[r], off);
        alr[r] += __shfl_xor(alr[r], off);
      }
    }
    if (m == 0) {
#pragma unroll
      for (int r = 0; r < 4; ++r) {
        l1part[w][mi * 16 + kg * 4 + r] = l1r[r];
        alpart[w][mi * 16 + kg * 4 + r] = alr[r];
      }
    }
  }
  __syncthreads();

  if (tid < ROWSB) {
    const float L = l1part[0][tid] + l1part[1][tid] + l1part[2][tid] + l1part[3][tid];
    const float A = alpart[0][tid] + alpart[1][tid] + alpart[2][tid] + alpart[3][tid];
    float c = lblLds[tid] ? (L - 2.f * A) / fmaxf(L, 1e-12f) : 0.f;
#pragma unroll
    for (int off = 1; off < 64; off <<= 1) c += __shfl_xor(c, off);
    if (tid == 0) atomicAdd(out, c);
  }
}

// ---------------- Diagnostic ablation kernels (write NOTHING) ----------------
// MODE bits: 1 = global loads, 2 = LDS writes, 4 = ds_read + MFMA.
// Same skeleton, grid 512, 4 waves, same barrier structure as cos_loss_k.
// Live-value retention via asm sinks (rule #17), REP repeats to rise above
// the ~58 us harness fill dispatches in the profile.
template<int MODE, int REP>
__global__ __launch_bounds__(256) void cos_diag_k(
    const float* __restrict__ feats,
    const short* __restrict__ cnb2) {
  const int tid = threadIdx.x;
  const int w = tid >> 6;
  const int lane = tid & 63;
  const int m = lane & 15;
  const int kg = lane >> 4;
  const int swzf = (m >> 1) & 3;
  const int rowBase = blockIdx.x * ROWSB;

  __shared__ short As[2][ROWSB][32];
  __shared__ short Bs[2][CPAD][32];

  const int arow = tid >> 2;
  const int akg  = tid & 3;
  const int aswz = (arow >> 1) & 3;
  const float* asrc = feats + (size_t)(rowBase + arow) * DIMS + akg * 8;
  const int bcol = tid;
  const int bswz = (bcol >> 1) & 3;
  const short* bsrc = cnb2 + bcol * KSTEP;

  f32x4 acc[4][4];
#pragma unroll
  for (int mi = 0; mi < 4; ++mi)
#pragma unroll
    for (int ni = 0; ni < 4; ++ni) acc[mi][ni] = (f32x4){0.f, 0.f, 0.f, 0.f};

  float ssq = 0.f;
  float fsum = 0.f;
  int isink = 0;
  float4 va = {0.f, 0.f, 0.f, 0.f}, vb = {0.f, 0.f, 0.f, 0.f};
  short8 b0 = (short8){0,0,0,0,0,0,0,0}, b1 = (short8){0,0,0,0,0,0,0,0};
  short8 b2 = (short8){0,0,0,0,0,0,0,0}, b3 = (short8){0,0,0,0,0,0,0,0};

#define D_LOAD(step) do {                                                \
    const float* ap_ = asrc + (step) * KSTEP;                            \
    va = *(const float4*)(ap_);                                          \
    vb = *(const float4*)(ap_ + 4);                                      \
    const short* bp_ = bsrc + (size_t)(step) * (CPAD * KSTEP);           \
    b0 = *(const short8*)(bp_ + 0);                                      \
    b1 = *(const short8*)(bp_ + 8);                                      \
    b2 = *(const short8*)(bp_ + 16);                                     \
    b3 = *(const short8*)(bp_ + 24);                                     \
  } while (0)

#define D_WRITE(buf) do {                                                \
    ssq += va.x*va.x + va.y*va.y + va.z*va.z + va.w*va.w;                \
    ssq += vb.x*vb.x + vb.y*vb.y + vb.z*vb.z + vb.w*vb.w;                \
    union { short8 s; unsigned u[4]; } p_;                               \
    p_.u[0] = pk_bf16(va.x, va.y); p_.u[1] = pk_bf16(va.z, va.w);        \
    p_.u[2] = pk_bf16(vb.x, vb.y); p_.u[3] = pk_bf16(vb.z, vb.w);        \
    *(short8*)(&As[(buf)][arow][(akg ^ aswz) * 8]) = p_.s;               \
    *(short8*)(&Bs[(buf)][bcol][(0 ^ bswz) * 8]) = b0;                   \
    *(short8*)(&Bs[(buf)][bcol][(1 ^ bswz) * 8]) = b1;                   \
    *(short8*)(&Bs[(buf)][bcol][(2 ^ bswz) * 8]) = b2;                   \
    *(short8*)(&Bs[(buf)][bcol][(3 ^ bswz) * 8]) = b3;                   \
  } while (0)

  // consume loaded regs when LDS-writes are off (prevents DCE of loads)
#define D_SINK() do {                                                    \
    fsum += va.x + va.y + va.z + va.w + vb.x + vb.y + vb.z + vb.w;       \
    isink ^= (int)b0[0] ^ (int)b1[1] ^ (int)b2[2] ^ (int)b3[3];          \
  } while (0)

#define D_COMPUTE(buf) do {                                              \
    short8 af[4], bf[4];                                                 \
    _Pragma("unroll")                                                    \
    for (int mi = 0; mi < 4; ++mi)                                       \
      af[mi] = *(const short8*)(&As[(buf)][mi * 16 + m][(kg ^ swzf) * 8]); \
    _Pragma("unroll")                                                    \
    for (int ni = 0; ni < 4; ++ni)                                       \
      bf[ni] = *(const short8*)(&Bs[(buf)][w * 64 + ni * 16 + m][(kg ^ swzf) * 8]); \
    _Pragma("unroll")                                                    \
    for (int mi = 0; mi < 4; ++mi)                                       \
      _Pragma("unroll")                                                  \
      for (int ni = 0; ni < 4; ++ni)                                     \
        acc[mi][ni] = __builtin_amdgcn_mfma_f32_16x16x32_bf16(           \
            af[mi], bf[ni], acc[mi][ni], 0, 0, 0);                       \
  } while (0)

  for (int rep = 0; rep < REP; ++rep) {
    if constexpr (MODE & 1) D_LOAD(0);
    if constexpr (MODE & 2) D_WRITE(0);
    if constexpr ((MODE & 1) && !(MODE & 2)) D_SINK();
    __syncthreads();
    for (int ks = 0; ks < NSTEP; ks += 2) {
      if constexpr (MODE & 1) { if (ks + 1 < NSTEP) D_LOAD(ks + 1); }
      if constexpr (MODE & 4) D_COMPUTE(0);
      if constexpr (MODE & 2) { if (ks + 1 < NSTEP) D_WRITE(1); }
      if constexpr ((MODE & 1) && !(MODE & 2)) D_SINK();
      __syncthreads();
      if constexpr (MODE & 1) { if (ks + 2 < NSTEP) D_LOAD(ks + 2); }
      if constexpr (MODE & 4) D_COMPUTE(1);
      if constexpr (MODE & 2) { if (ks + 2 < NSTEP) D_WRITE(0); }
      if constexpr ((MODE & 1) && !(MODE & 2)) D_SINK();
      __syncthreads();
    }
  }

#undef D_LOAD
#undef D_WRITE
#undef D_SINK
#undef D_COMPUTE

  // final live sinks — nothing is stored to memory
#pragma unroll
  for (int mi = 0; mi < 4; ++mi)
#pragma unroll
    for (int ni = 0; ni < 4; ++ni)
#pragma unroll
      for (int r = 0; r < 4; ++r) fsum += acc[mi][ni][r];
  fsum += ssq + (float)isink;
  asm volatile("" :: "v"(fsum));
}

extern "C" void kernel_launch(void* const* d_in, const int* in_sizes, int n_in,
                              void* d_out, int out_size, void* d_ws, size_t ws_size,
                              hipStream_t stream) {
  const float* feats = (const float*)d_in[0];
  const float* centers = (const float*)d_in[1];
  const int* labels = (const int*)d_in[2];
  const int* labelled = (const int*)d_in[3];
  float* out = (float*)d_out;
  short* cnb2 = (short*)d_ws;  // [24][256][32] bf16 = 393216 B

  prep_centers_k<<<CPAD, 256, 0, stream>>>(centers, cnb2, out);
  cos_loss_k<<<NROWS / ROWSB, 256, 0, stream>>>(feats, cnb2, labels, labelled, out);

  // ---- diagnostics (timing-sacrificial; read per-dispatch rows in rocprof) ----
  cos_diag_k<7, 4><<<NROWS / ROWSB, 256, 0, stream>>>(feats, cnb2);   // FULL    x4
  cos_diag_k<3, 6><<<NROWS / ROWSB, 256, 0, stream>>>(feats, cnb2);   // STAGE   x6
  cos_diag_k<4, 16><<<NROWS / ROWSB, 256, 0, stream>>>(feats, cnb2);  // COMPUTE x16
  cos_diag_k<1, 12><<<NROWS / ROWSB, 256, 0, stream>>>(feats, cnb2);  // STREAM  x12
}

// Round 13
// 35.898 us; speedup vs baseline: 10.1715x; 10.1715x over previous
//
#include <hip/hip_runtime.h>
#include <hip/hip_bf16.h>

// Problem constants: B=32768, D=768, C=200.
#define NROWS 32768
#define DIMS  768
#define NC    200
#define CPAD  256
#define KSTEP 32
#define NSTEP (DIMS / KSTEP)   // 24
#define ROWSB 64               // M-tile rows per block -> grid 512

typedef __attribute__((ext_vector_type(8))) short short8;   // 8 bf16
typedef __attribute__((ext_vector_type(4))) float f32x4;

#define WAITV4 asm volatile("s_waitcnt vmcnt(4)" ::: "memory")
#define WAITV2 asm volatile("s_waitcnt vmcnt(2)" ::: "memory")
#define WAITL0 asm volatile("s_waitcnt lgkmcnt(0)" ::: "memory")
#define BAR    __builtin_amdgcn_s_barrier()

__device__ __forceinline__ unsigned pk_bf16(float lo, float hi) {
  union { __hip_bfloat162 h; unsigned u; } c;
  c.h = __float22bfloat162_rn(make_float2(lo, hi));
  return c.u;
}

// Kernel 1 (round-6 plain version): L2-normalize centers -> bf16, K-blocked:
// (c,d) -> cnb2[(d>>5)*CPAD*KSTEP + c*KSTEP + (d&31)]; rows >= NC zero. Zeroes out.
__global__ __launch_bounds__(256) void prep_centers_k(const float* __restrict__ centers,
                                                      short* __restrict__ cnb2,
                                                      float* __restrict__ out) {
  const int c = blockIdx.x;
  const int tid = threadIdx.x;
  if (c == 0 && tid == 0) out[0] = 0.f;
  if (c >= NC) {
    for (int d = tid; d < DIMS; d += 256)
      cnb2[(d >> 5) * (CPAD * KSTEP) + c * KSTEP + (d & 31)] = 0;
    return;
  }
  float ssq = 0.f;
  for (int d = tid; d < DIMS; d += 256) {
    float v = centers[c * DIMS + d];
    ssq += v * v;
  }
#pragma unroll
  for (int off = 32; off > 0; off >>= 1) ssq += __shfl_down(ssq, off);
  __shared__ float red[4];
  const int wid = tid >> 6, lane = tid & 63;
  if (lane == 0) red[wid] = ssq;
  __syncthreads();
  const float tot = red[0] + red[1] + red[2] + red[3];
  const float inv = 1.f / fmaxf(sqrtf(tot), 1e-8f);
  for (int d = tid; d < DIMS; d += 256) {
    const float v = centers[c * DIMS + d] * inv;
    union { __hip_bfloat16 h; short s; } cv;
    cv.h = __float2bfloat16(v);
    cnb2[(d >> 5) * (CPAD * KSTEP) + c * KSTEP + (d & 31)] = cv.s;
  }
}

// Kernel 2: PRODUCER-CONSUMER wave specialization. 512 thr = 8 waves.
//   waves 0-3 CONSUMERS: wave tile 64x64; A-frags from LDS (dbuf, quad-swizzled);
//     B-frags direct from L2-resident cnb2 (1 KB coalesced per frag), two named
//     slots, full-phase prefetch lead; counted vmcnt(4) + raw s_barrier.
//   waves 4-7 PRODUCERS: A staging only (fp32 load depth-2 slots -> pk_bf16 cvt
//     + ssq -> one ds_write); counted vmcnt(2) + lgkmcnt(0) + raw s_barrier.
// B never touches LDS: LDS traffic/CU/step drops 104 -> ~40 instr.
// MFMA frag mapping (verified rounds 2-12): A lane=A[m][kg*8+j];
// B lane=B[kg*8+j][m]; D: col=m, row=kg*4+reg.
__global__ __launch_bounds__(512, 4) void cos_loss_k(
    const float* __restrict__ feats,
    const short* __restrict__ cnb2,
    const int* __restrict__ labels,
    const int* __restrict__ labelled,
    float* __restrict__ out) {
  const int tid = threadIdx.x;
  const int wid = tid >> 6;          // 0-3 consumers, 4-7 producers
  const int lane = tid & 63;
  const int rowBase = blockIdx.x * ROWSB;

  __shared__ short As[2][ROWSB][32];   // 8 KB, dbuf
  __shared__ float invs[ROWSB];
  __shared__ int   labLds[ROWSB];
  __shared__ int   lblLds[ROWSB];
  __shared__ float l1part[4][ROWSB];
  __shared__ float alpart[4][ROWSB];

  if (tid < ROWSB) {
    labLds[tid] = labels[rowBase + tid];
    lblLds[tid] = labelled[rowBase + tid];
  }

  if (wid < 4) {
    // =========================== CONSUMER ===========================
    const int m = lane & 15;
    const int kg = lane >> 4;
    const int rdq = (kg ^ ((m >> 1) & 3)) * 8;   // swizzled A-frag quad offset
    // B frag base: col = wid*64 + m, within-frag offset kg*8 shorts
    const short* bp = cnb2 + (size_t)(wid * 64 + m) * KSTEP + kg * 8;

    f32x4 acc[4][4];
#pragma unroll
    for (int mi = 0; mi < 4; ++mi)
#pragma unroll
      for (int ni = 0; ni < 4; ++ni) acc[mi][ni] = (f32x4){0.f, 0.f, 0.f, 0.f};

    short8 B0[4], B1[4];

#define LOADB(B, s) do {                                                 \
    const short* bs_ = bp + (size_t)(s) * (CPAD * KSTEP);                \
    B[0] = *(const short8*)(bs_ + 0 * (16 * KSTEP));                     \
    B[1] = *(const short8*)(bs_ + 1 * (16 * KSTEP));                     \
    B[2] = *(const short8*)(bs_ + 2 * (16 * KSTEP));                     \
    B[3] = *(const short8*)(bs_ + 3 * (16 * KSTEP));                     \
  } while (0)

#define CCOMPUTE(ab, B) do {                                             \
    short8 af[4];                                                        \
    _Pragma("unroll")                                                    \
    for (int mi = 0; mi < 4; ++mi)                                       \
      af[mi] = *(const short8*)(&As[(ab)][mi * 16 + m][rdq]);            \
    _Pragma("unroll")                                                    \
    for (int mi = 0; mi < 4; ++mi)                                       \
      _Pragma("unroll")                                                  \
      for (int ni = 0; ni < 4; ++ni)                                     \
        acc[mi][ni] = __builtin_amdgcn_mfma_f32_16x16x32_bf16(           \
            af[mi], B[ni], acc[mi][ni], 0, 0, 0);                        \
  } while (0)

    // prologue: B slots for steps 0 and 1 (8 loads); wait slot0 only
    LOADB(B0, 0);
    LOADB(B1, 1);
    WAITV4;            // B0 ready; B1's 4 in flight
    BAR;               // barrier 0: A buf0 published by producers

    for (int s = 0; s < NSTEP; s += 2) {
      // phase s (even): compute step s from As[0] + B0
      CCOMPUTE(0, B0);
      { const int s2 = (s + 2 < NSTEP) ? s + 2 : NSTEP - 1; LOADB(B0, s2); }
      WAITV4;          // B1 (step s+1) ready; B0 (s+2) in flight
      BAR;
      // phase s+1 (odd): compute step s+1 from As[1] + B1
      CCOMPUTE(1, B1);
      { const int s3 = (s + 3 < NSTEP) ? s + 3 : NSTEP - 1; LOADB(B1, s3); }
      WAITV4;          // B0 (step s+2) ready
      BAR;
    }
#undef LOADB
#undef CCOMPUTE

    BAR;               // barrier 26: producers published invs

    // epilogue: per-row l1 and label-|cos|
#pragma unroll
    for (int mi = 0; mi < 4; ++mi) {
      float l1r[4] = {0.f, 0.f, 0.f, 0.f};
      float alr[4] = {0.f, 0.f, 0.f, 0.f};
      float iv[4];
      int labr[4];
#pragma unroll
      for (int r = 0; r < 4; ++r) {
        const int row = mi * 16 + kg * 4 + r;
        iv[r] = invs[row];
        labr[r] = labLds[row];
      }
#pragma unroll
      for (int ni = 0; ni < 4; ++ni) {
        const int col = wid * 64 + ni * 16 + m;
#pragma unroll
        for (int r = 0; r < 4; ++r) {
          const float a = fabsf(acc[mi][ni][r] * iv[r]);
          l1r[r] += a;
          if (col == labr[r]) alr[r] += a;
        }
      }
#pragma unroll
      for (int r = 0; r < 4; ++r) {
#pragma unroll
        for (int off = 1; off < 16; off <<= 1) {
          l1r[r] += __shfl_xor(l1r[r], off);
          alr[r] += __shfl_xor(alr[r], off);
        }
      }
      if (m == 0) {
#pragma unroll
        for (int r = 0; r < 4; ++r) {
          l1part[wid][mi * 16 + kg * 4 + r] = l1r[r];
          alpart[wid][mi * 16 + kg * 4 + r] = alr[r];
        }
      }
    }
  } else {
    // =========================== PRODUCER ===========================
    const int pt = (wid - 4) * 64 + lane;    // 0..255
    const int arow = pt >> 2;                // 4 thr/row
    const int aq   = pt & 3;
    const int aswz = (arow >> 1) & 3;
    const float* asrc = feats + (size_t)(rowBase + arow) * DIMS + aq * 8;
    short* adst0 = &As[0][arow][(aq ^ aswz) * 8];
    short* adst1 = &As[1][arow][(aq ^ aswz) * 8];

    float ssq = 0.f;
    float4 S0lo, S0hi, S1lo, S1hi;

#define LOADA(P, s) do {                                                 \
    const float* ap_ = asrc + (s) * KSTEP;                               \
    P##lo = *(const float4*)(ap_);                                       \
    P##hi = *(const float4*)(ap_ + 4);                                   \
  } while (0)

#define WRITEA(P, dst, guard) do {                                       \
    if (guard) {                                                         \
      ssq += P##lo.x*P##lo.x + P##lo.y*P##lo.y                           \
           + P##lo.z*P##lo.z + P##lo.w*P##lo.w;                          \
      ssq += P##hi.x*P##hi.x + P##hi.y*P##hi.y                           \
           + P##hi.z*P##hi.z + P##hi.w*P##hi.w;                          \
    }                                                                    \
    union { short8 s8; unsigned u[4]; } p_;                              \
    p_.u[0] = pk_bf16(P##lo.x, P##lo.y);                                 \
    p_.u[1] = pk_bf16(P##lo.z, P##lo.w);                                 \
    p_.u[2] = pk_bf16(P##hi.x, P##hi.y);                                 \
    p_.u[3] = pk_bf16(P##hi.z, P##hi.w);                                 \
    *(short8*)(dst) = p_.s8;                                             \
  } while (0)

    // prologue: load steps 0,1; write step 0 -> buf0
    LOADA(S0, 0);
    LOADA(S1, 1);
    WAITV2;            // S0 ready; S1 in flight
    WRITEA(S0, adst0, true);
    WAITL0;
    BAR;               // barrier 0

    for (int s = 0; s < NSTEP; s += 2) {
      // phase s (even): prefetch s+2 into S0; publish step s+1 (S1) -> buf1
      { const int s2 = (s + 2 < NSTEP) ? s + 2 : NSTEP - 1; LOADA(S0, s2); }
      WAITV2;          // S1 (step s+1) ready; S0 (s+2) in flight
      WRITEA(S1, adst1, (s + 1 < NSTEP));
      WAITL0;
      BAR;
      // phase s+1 (odd): prefetch s+3 into S1; publish step s+2 (S0) -> buf0
      { const int s3 = (s + 3 < NSTEP) ? s + 3 : NSTEP - 1; LOADA(S1, s3); }
      WAITV2;          // S0 (step s+2) ready
      WRITEA(S0, adst0, (s + 2 < NSTEP));
      WAITL0;
      BAR;
    }
#undef LOADA
#undef WRITEA

    // row inverse norms: reduce over the 4 staging lanes of each row
    ssq += __shfl_xor(ssq, 1);
    ssq += __shfl_xor(ssq, 2);
    if ((lane & 3) == 0) invs[arow] = 1.f / fmaxf(sqrtf(ssq), 1e-8f);
    WAITL0;
    BAR;               // barrier 26: invs published
  }

  __syncthreads();     // barrier 27: l1part/alpart published

  if (tid < ROWSB) {
    const float L = l1part[0][tid] + l1part[1][tid] + l1part[2][tid] + l1part[3][tid];
    const float A = alpart[0][tid] + alpart[1][tid] + alpart[2][tid] + alpart[3][tid];
    float c = lblLds[tid] ? (L - 2.f * A) / fmaxf(L, 1e-12f) : 0.f;
#pragma unroll
    for (int off = 1; off < 64; off <<= 1) c += __shfl_xor(c, off);
    if (tid == 0) atomicAdd(out, c);
  }
}

extern "C" void kernel_launch(void* const* d_in, const int* in_sizes, int n_in,
                              void* d_out, int out_size, void* d_ws, size_t ws_size,
                              hipStream_t stream) {
  const float* feats = (const float*)d_in[0];
  const float* centers = (const float*)d_in[1];
  const int* labels = (const int*)d_in[2];
  const int* labelled = (const int*)d_in[3];
  float* out = (float*)d_out;
  short* cnb2 = (short*)d_ws;  // [24][256][32] bf16 = 393216 B

  prep_centers_k<<<CPAD, 256, 0, stream>>>(centers, cnb2, out);
  cos_loss_k<<<NROWS / ROWSB, 512, 0, stream>>>(feats, cnb2, labels, labelled, out);
}